// Round 8
// baseline (206.874 us; speedup 1.0000x reference)
//
#include <hip/hip_runtime.h>
#include <math.h>

// Problem constants (from reference)
#define N_IMG 2
#define R_PROP 256
#define G_GT 64
#define C_CH 1024
#define FH 50
#define FW 80
#define P_POOL 14
#define NCLS 80
#define IMG_W_F 1280.0f
#define IMG_H_F 800.0f
#define SCALE_F 0.0625f
#define SCORE_TH_F 0.05f
#define NMS_TH_F 0.5f
#define IOU_TH_F 0.5f
#define MAX_DET_I 100
#define SCALE_CLAMP_F 4.135166556742356f  // log(1000/16)

// ---------------------------------------------------------------------------
// Kernel 1 (prep): y-center sort (perm for XCD swizzle) + gt matching.
// ---------------------------------------------------------------------------
__global__ __launch_bounds__(512) void prep_kernel(
    const float* __restrict__ proposals,  // (N,R,4)
    const float* __restrict__ gt_boxes,   // (N,G,4)
    int* __restrict__ perm,               // (N*R)
    float* __restrict__ out_idx,          // (N,R) as float
    float* __restrict__ out_lbl) {        // (N,R) as float
  const int t = threadIdx.x;      // 0..511
  const int n = t >> 8;
  __shared__ float cy[N_IMG * R_PROP];
  const float* pb = proposals + (size_t)t * 4;
  float bx1 = pb[0], by1 = pb[1], bx2 = pb[2], by2 = pb[3];
  cy[t] = by1 + by2;              // 2*cy, monotone in cy
  __syncthreads();

  // y-rank within image
  {
    float my = cy[t];
    int rk = 0;
    const int base = n * R_PROP;
#pragma unroll 8
    for (int j = base; j < base + R_PROP; ++j) {
      float cj = cy[j];
      rk += (cj < my) || (cj == my && j < t);
    }
    perm[base + rk] = t & 255;
  }

  // gt matching
  {
    float area_b = (bx2 - bx1) * (by2 - by1);
    float best = -1.0f;
    int bidx = 0;
    const float* gt = gt_boxes + (size_t)n * G_GT * 4;
#pragma unroll 4
    for (int g = 0; g < G_GT; ++g) {
      float gx1 = gt[g * 4 + 0], gy1 = gt[g * 4 + 1];
      float gx2 = gt[g * 4 + 2], gy2 = gt[g * 4 + 3];
      float area_a = (gx2 - gx1) * (gy2 - gy1);
      float ix1 = fmaxf(gx1, bx1), iy1 = fmaxf(gy1, by1);
      float ix2 = fminf(gx2, bx2), iy2 = fminf(gy2, by2);
      float iw = fmaxf(ix2 - ix1, 0.0f), ih = fmaxf(iy2 - iy1, 0.0f);
      float inter = iw * ih;
      float iou = inter / fmaxf(area_a + area_b - inter, 1e-9f);
      if (iou > best) { best = iou; bidx = g; }
    }
    out_idx[t] = (float)bidx;
    out_lbl[t] = (best >= IOU_TH_F) ? 1.0f : 0.0f;
  }
}

// ---------------------------------------------------------------------------
// Kernel 2 (roi + partial heads): TWO blocks per proposal (channel halves),
// 1024 threads each. Half h handles 512 channels; row split is 8-way
// (g = t>>7, 128 float4 slots/thread-group) -> worst-case per-thread loads
// 126 -> 63 vs R7. Both halves of a proposal land on the same XCD (disjoint
// bytes, no extra fetch). Phase 2 computes partial head dots over K=512 from
// LDS and writes part[p][h][85] (no bias); softmax/decode move to nms.
// ---------------------------------------------------------------------------
__global__ __launch_bounds__(1024) void roihead_kernel(
    const float* __restrict__ features,   // (N, FH, FW, C)
    const float* __restrict__ proposals,  // (N, R, 4)
    const int* __restrict__ perm,         // (N*R) y-sorted order
    const float* __restrict__ W_cls,      // (C, 81)
    const float* __restrict__ W_box,      // (C, 4)
    float* __restrict__ part) {           // (N*R, 2, 85) partial logits
  const int b = blockIdx.x;             // 0..1023
  const int xcd = b & 7;
  const int slot = b >> 3;              // 0..127
  const int n = xcd >> 2;               // image
  const int band = xcd & 3;
  const int h = slot & 1;               // channel half
  const int blk = n * R_PROP + perm[n * R_PROP + band * 64 + (slot >> 1)];

  const float* feat = features + (size_t)n * (FH * FW * C_CH) + h * (C_CH / 2);
  const int t = threadIdx.x;
  const int c4 = t & 127;               // float4 slot within half (0..127)
  const int g = t >> 7;                 // 0..7 row group

  __shared__ float s_Wy[FH];
  __shared__ float s_Wx[FW];
  __shared__ int s_b[4];                // y_lo, y_hi, x_lo, x_hi
  __shared__ float4 s_red[7][128];
  __shared__ __align__(16) float sf[C_CH / 2];
  __shared__ float s_part[12][85];

  if (t < FH) s_Wy[t] = 0.0f;
  if (t >= 128 && t < 128 + FW) s_Wx[t - 128] = 0.0f;
  __syncthreads();

  if (t < 2 * P_POOL) {
    const float* pb = proposals + (size_t)blk * 4;
    bool isY = t < P_POOL;
    int i = isY ? t : t - P_POOL;
    float lo = isY ? pb[1] : pb[0];
    float hi = isY ? pb[3] : pb[2];
    float limit = isY ? (float)(FH - 1) : (float)(FW - 1);
    float b1 = lo * SCALE_F, b2 = hi * SCALE_F;
    float bs = (b2 - b1) * (1.0f / P_POOL);
    float gg = b1 + ((float)i + 0.5f) * bs - 0.5f;
    gg = fminf(fmaxf(gg, 0.0f), limit);
    float fl = floorf(gg);
    int i0 = (int)fl;
    int i1 = min(i0 + 1, (int)limit);
    float l = gg - fl;
    if (isY) {
      atomicAdd(&s_Wy[i0], 1.0f - l);
      atomicAdd(&s_Wy[i1], l);
      if (i == 0) s_b[0] = i0;
      if (i == P_POOL - 1) s_b[1] = i1;
    } else {
      atomicAdd(&s_Wx[i0], 1.0f - l);
      atomicAdd(&s_Wx[i1], l);
      if (i == 0) s_b[2] = i0;
      if (i == P_POOL - 1) s_b[3] = i1;
    }
  }
  __syncthreads();

  // ---- phase 1: ROI accumulate, 8-way row split over 512 channels ----
  {
    const int ylo = s_b[0], yhi = s_b[1], xlo = s_b[2], xhi = s_b[3];
    float4 acc = make_float4(0.f, 0.f, 0.f, 0.f);
    for (int y = ylo + g; y <= yhi; y += 8) {
      float wy = s_Wy[y];
      const float4* row = (const float4*)(feat + (size_t)y * (FW * C_CH)) + c4;
#pragma unroll 8
      for (int x = xlo; x <= xhi; ++x) {
        float w = wy * s_Wx[x];
        float4 f = row[x * (C_CH / 4)];
        acc.x += w * f.x;
        acc.y += w * f.y;
        acc.z += w * f.z;
        acc.w += w * f.w;
      }
    }
    if (g > 0) s_red[g - 1][c4] = acc;
    __syncthreads();
    if (g == 0) {
      const float inv = 1.0f / (float)(P_POOL * P_POOL);
#pragma unroll
      for (int p = 0; p < 7; ++p) {
        float4 a = s_red[p][c4];
        acc.x += a.x; acc.y += a.y; acc.z += a.z; acc.w += a.w;
      }
      ((float4*)sf)[c4] =
          make_float4(acc.x * inv, acc.y * inv, acc.z * inv, acc.w * inv);
    }
    __syncthreads();
  }

  // ---- phase 2: partial heads GEMV over this half's K=512, 12-way split ----
  const int kq = t / 85;        // 0..12 (t>=1020 -> 12, inactive)
  const int j = t - kq * 85;
  if (kq < 12) {
    float acc = 0.0f;
    const int kbase = h * (C_CH / 2);
    if (j < 81) {
      const float* __restrict__ w = W_cls + (size_t)kbase * 81 + j;
#pragma unroll 8
      for (int k = kq; k < C_CH / 2; k += 12) acc += sf[k] * w[k * 81];
    } else {
      const float* __restrict__ w = W_box + (size_t)kbase * 4 + (j - 81);
#pragma unroll 8
      for (int k = kq; k < C_CH / 2; k += 12) acc += sf[k] * w[k * 4];
    }
    s_part[kq][j] = acc;
  }
  __syncthreads();

  if (t < 85) {
    float acc = 0.0f;
#pragma unroll
    for (int p = 0; p < 12; ++p) acc += s_part[p][t];
    part[(size_t)blk * 170 + h * 85 + t] = acc;
  }
}

// ---------------------------------------------------------------------------
// Kernel 3: logits assembly + softmax + box decode + greedy NMS + top-100.
// One block per image, 1024 threads (i = u&255 proposal, q = u>>8 quarter).
// Prologue: (i,q) computes partial max / exp-sum over logit subset j = q mod 4
// (two passes, no big register arrays); q==0 finishes score + decode.
// Then the R7 NMS flow (rank, IoU bitmask, branchless serial greedy, top-100).
// ---------------------------------------------------------------------------
__global__ __launch_bounds__(1024) void nms_kernel(
    const float* __restrict__ part,       // (N*R, 2, 85)
    const float* __restrict__ proposals,  // (N,R,4)
    const float* __restrict__ b_cls,      // (81)
    const float* __restrict__ b_box,      // (4)
    float* __restrict__ det) {            // (N, R, 6)
  const int n = blockIdx.x;
  const int u = threadIdx.x;
  const int i = u & 255;
  const int q = u >> 8;           // 0..3
  const int j40 = q * 16;         // float4 index start for this quarter

  __shared__ __align__(16) float ss[R_PROP];     // scores, original order
  __shared__ float4 sbs[R_PROP];                 // sorted boxes
  __shared__ int s_part[4 * R_PROP];             // partial rank counts
  __shared__ int s_rank[R_PROP];
  __shared__ __align__(16) unsigned long long s_mask[R_PROP * 4];
  __shared__ unsigned long long s_keep[4];
  __shared__ __align__(16) float sm[R_PROP];     // masked scores, orig order
  __shared__ float s_f1[4 * R_PROP];             // partial max / expsum
  __shared__ float s_f2[4 * R_PROP];             // partial fg max
  __shared__ float s_m[R_PROP];                  // per-proposal max

  const float* pp = part + ((size_t)n * R_PROP + i) * 170;

  // pass 1: partial max over logits j = q, q+4, ...
  {
    float pm = -INFINITY, pf = -INFINITY;
    for (int j = q; j < 81; j += 4) {
      float v = pp[j] + pp[85 + j] + b_cls[j];
      pm = fmaxf(pm, v);
      if (j < NCLS) pf = fmaxf(pf, v);
    }
    s_f1[q * R_PROP + i] = pm;
    s_f2[q * R_PROP + i] = pf;
  }
  __syncthreads();
  if (q == 0) {
    float m = fmaxf(fmaxf(s_f1[i], s_f1[R_PROP + i]),
                    fmaxf(s_f1[2 * R_PROP + i], s_f1[3 * R_PROP + i]));
    s_m[i] = m;
  }
  __syncthreads();

  // pass 2: partial exp-sum
  {
    float mm = s_m[i];
    float ps = 0.0f;
    for (int j = q; j < 81; j += 4) {
      float v = pp[j] + pp[85 + j] + b_cls[j];
      ps += expf(v - mm);
    }
    s_f1[q * R_PROP + i] = ps;
  }
  __syncthreads();

  float4 myb;
  float mys;
  if (q == 0) {
    float mm = s_m[i];
    float sum = s_f1[i] + s_f1[R_PROP + i] + s_f1[2 * R_PROP + i] +
                s_f1[3 * R_PROP + i];
    float fgm = fmaxf(fmaxf(s_f2[i], s_f2[R_PROP + i]),
                      fmaxf(s_f2[2 * R_PROP + i], s_f2[3 * R_PROP + i]));
    mys = expf(fgm - mm) / sum;

    // box decode
    const float* pb = proposals + ((size_t)n * R_PROP + i) * 4;
    float w = pb[2] - pb[0], h = pb[3] - pb[1];
    float cx = pb[0] + 0.5f * w, cy = pb[1] + 0.5f * h;
    float d0 = pp[81] + pp[85 + 81] + b_box[0];
    float d1 = pp[82] + pp[85 + 82] + b_box[1];
    float d2 = pp[83] + pp[85 + 83] + b_box[2];
    float d3 = pp[84] + pp[85 + 84] + b_box[3];
    float dx = d0 * 0.1f;
    float dy = d1 * 0.1f;
    float dw = fminf(d2 * 0.2f, SCALE_CLAMP_F);
    float dh = fminf(d3 * 0.2f, SCALE_CLAMP_F);
    float pcx = dx * w + cx, pcy = dy * h + cy;
    float pw = expf(dw) * w, ph = expf(dh) * h;
    myb.x = fminf(fmaxf(pcx - 0.5f * pw, 0.0f), IMG_W_F);
    myb.y = fminf(fmaxf(pcy - 0.5f * ph, 0.0f), IMG_H_F);
    myb.z = fminf(fmaxf(pcx + 0.5f * pw, 0.0f), IMG_W_F);
    myb.w = fminf(fmaxf(pcy + 0.5f * ph, 0.0f), IMG_H_F);
    ss[i] = mys;
  }
  __syncthreads();

  // stable descending rank (ties by original index): float4 loads, 16/thread
  {
    float s = ss[i];
    int cnt = 0;
#pragma unroll
    for (int j4 = j40; j4 < j40 + 16; ++j4) {
      float4 v = ((const float4*)ss)[j4];
      int jb = j4 * 4;
      cnt += (v.x > s) || (v.x == s && jb + 0 < i);
      cnt += (v.y > s) || (v.y == s && jb + 1 < i);
      cnt += (v.z > s) || (v.z == s && jb + 2 < i);
      cnt += (v.w > s) || (v.w == s && jb + 3 < i);
    }
    s_part[q * R_PROP + i] = cnt;
  }
  __syncthreads();
  if (q == 0) {
    int rk = s_part[i] + s_part[R_PROP + i] + s_part[2 * R_PROP + i] +
             s_part[3 * R_PROP + i];
    s_rank[i] = rk;
    sbs[rk] = myb;
  }
  __syncthreads();

  // phase 1: thread (i,q) computes mask word q of sorted box i vs sorted j
  {
    float4 bi = sbs[i];
    float area_i = (bi.z - bi.x) * (bi.w - bi.y);
    unsigned long long m = 0;
    const int j0 = q * 64;
#pragma unroll 8
    for (int jj = 0; jj < 64; ++jj) {
      float4 bj = sbs[j0 + jj];
      float area_j = (bj.z - bj.x) * (bj.w - bj.y);
      float ix1 = fmaxf(bi.x, bj.x), iy1 = fmaxf(bi.y, bj.y);
      float ix2 = fminf(bi.z, bj.z), iy2 = fminf(bi.w, bj.w);
      float iw = fmaxf(ix2 - ix1, 0.0f), ih = fmaxf(iy2 - iy1, 0.0f);
      float inter = iw * ih;
      float iou = inter / fmaxf(area_i + area_j - inter, 1e-9f);
      m |= (iou > NMS_TH_F) ? (1ull << jj) : 0ull;
    }
    s_mask[i * 4 + q] = m;
  }
  __syncthreads();

  // phase 2: branchless serial greedy pass over sorted order (thread 0).
  if (u == 0) {
    unsigned long long K0 = ~0ull, K1 = ~0ull, K2 = ~0ull, K3 = ~0ull;
#pragma unroll 16
    for (int b = 1; b < 64; ++b) {
      unsigned long long m0 = s_mask[(size_t)b * 4 + 0];
      unsigned long long sup = m0 & K0 & ((1ull << b) - 1ull);
      K0 = sup ? (K0 & ~(1ull << b)) : K0;
    }
#pragma unroll 16
    for (int b = 0; b < 64; ++b) {
      const unsigned long long* mi = &s_mask[(size_t)(64 + b) * 4];
      unsigned long long m0 = mi[0], m1 = mi[1];
      unsigned long long sup = (m0 & K0) | (m1 & K1 & ((1ull << b) - 1ull));
      K1 = sup ? (K1 & ~(1ull << b)) : K1;
    }
#pragma unroll 16
    for (int b = 0; b < 64; ++b) {
      const unsigned long long* mi = &s_mask[(size_t)(128 + b) * 4];
      unsigned long long m0 = mi[0], m1 = mi[1], m2 = mi[2];
      unsigned long long sup =
          (m0 & K0) | (m1 & K1) | (m2 & K2 & ((1ull << b) - 1ull));
      K2 = sup ? (K2 & ~(1ull << b)) : K2;
    }
#pragma unroll 16
    for (int b = 0; b < 64; ++b) {
      const unsigned long long* mi = &s_mask[(size_t)(192 + b) * 4];
      unsigned long long m0 = mi[0], m1 = mi[1], m2 = mi[2], m3 = mi[3];
      unsigned long long sup = (m0 & K0) | (m1 & K1) | (m2 & K2) |
                               (m3 & K3 & ((1ull << b) - 1ull));
      K3 = sup ? (K3 & ~(1ull << b)) : K3;
    }
    s_keep[0] = K0; s_keep[1] = K1; s_keep[2] = K2; s_keep[3] = K3;
  }
  __syncthreads();

  bool kept = false;
  if (q == 0) {
    int rk = s_rank[i];
    kept = ((s_keep[rk >> 6] >> (rk & 63)) & 1ull) && (mys > SCORE_TH_F);
    sm[i] = kept ? mys : -INFINITY;
  }
  __syncthreads();

  // top-100 rank over masked scores: float4 loads, 16/thread
  {
    float mym = sm[i];
    int cnt = 0;
#pragma unroll
    for (int j4 = j40; j4 < j40 + 16; ++j4) {
      float4 v = ((const float4*)sm)[j4];
      int jb = j4 * 4;
      cnt += (v.x > mym) || (v.x == mym && jb + 0 < i);
      cnt += (v.y > mym) || (v.y == mym && jb + 1 < i);
      cnt += (v.z > mym) || (v.z == mym && jb + 2 < i);
      cnt += (v.w > mym) || (v.w == mym && jb + 3 < i);
    }
    s_part[q * R_PROP + i] = cnt;
  }
  __syncthreads();

  if (q == 0) {
    int rk2 = s_part[i] + s_part[R_PROP + i] + s_part[2 * R_PROP + i] +
              s_part[3 * R_PROP + i];
    kept = kept && (rk2 < MAX_DET_I);
    float* dr = det + ((size_t)n * R_PROP + i) * 6;
    dr[0] = myb.x; dr[1] = myb.y; dr[2] = myb.z; dr[3] = myb.w;
    dr[4] = mys;
    dr[5] = kept ? 1.0f : 0.0f;
  }
}

// ---------------------------------------------------------------------------
extern "C" void kernel_launch(void* const* d_in, const int* in_sizes, int n_in,
                              void* d_out, int out_size, void* d_ws, size_t ws_size,
                              hipStream_t stream) {
  const float* features  = (const float*)d_in[0];  // (2,50,80,1024)
  const float* proposals = (const float*)d_in[1];  // (2,256,4)
  const float* gt_boxes  = (const float*)d_in[2];  // (2,64,4)
  // d_in[3] gt_classes: unused by reference outputs
  const float* W_cls = (const float*)d_in[4];      // (1024,81)
  const float* b_cls = (const float*)d_in[5];      // (81)
  const float* W_box = (const float*)d_in[6];      // (1024,4)
  const float* b_box = (const float*)d_in[7];      // (4)

  float* out = (float*)d_out;
  // out layout: det [0,3072) | matched_idxs [3072,3584) | match_labels [3584,4096)
  float* out_det = out;
  float* out_idx = out + N_IMG * R_PROP * 6;
  float* out_lbl = out_idx + N_IMG * R_PROP;

  // workspace layout
  float* part = (float*)d_ws;                        // 512*170 partial logits
  int*   perm = (int*)(part + (size_t)N_IMG * R_PROP * 170);  // 512

  prep_kernel<<<1, 512, 0, stream>>>(proposals, gt_boxes, perm, out_idx, out_lbl);
  roihead_kernel<<<2 * N_IMG * R_PROP, 1024, 0, stream>>>(
      features, proposals, perm, W_cls, W_box, part);
  nms_kernel<<<N_IMG, 1024, 0, stream>>>(part, proposals, b_cls, b_box, out_det);
}

// Round 9
// 165.486 us; speedup vs baseline: 1.2501x; 1.2501x over previous
//
#include <hip/hip_runtime.h>
#include <math.h>

// Problem constants (from reference)
#define N_IMG 2
#define R_PROP 256
#define G_GT 64
#define C_CH 1024
#define FH 50
#define FW 80
#define P_POOL 14
#define NCLS 80
#define IMG_W_F 1280.0f
#define IMG_H_F 800.0f
#define SCALE_F 0.0625f
#define SCORE_TH_F 0.05f
#define NMS_TH_F 0.5f
#define IOU_TH_F 0.5f
#define MAX_DET_I 100
#define SCALE_CLAMP_F 4.135166556742356f  // log(1000/16)

// ---------------------------------------------------------------------------
// Kernel 1 (prep): y-center sort (perm for XCD swizzle) + gt matching.
// ---------------------------------------------------------------------------
__global__ __launch_bounds__(512) void prep_kernel(
    const float* __restrict__ proposals,  // (N,R,4)
    const float* __restrict__ gt_boxes,   // (N,G,4)
    int* __restrict__ perm,               // (N*R)
    float* __restrict__ out_idx,          // (N,R) as float
    float* __restrict__ out_lbl) {        // (N,R) as float
  const int t = threadIdx.x;      // 0..511
  const int n = t >> 8;
  __shared__ float cy[N_IMG * R_PROP];
  const float* pb = proposals + (size_t)t * 4;
  float bx1 = pb[0], by1 = pb[1], bx2 = pb[2], by2 = pb[3];
  cy[t] = by1 + by2;              // 2*cy, monotone in cy
  __syncthreads();

  // y-rank within image
  {
    float my = cy[t];
    int rk = 0;
    const int base = n * R_PROP;
#pragma unroll 8
    for (int j = base; j < base + R_PROP; ++j) {
      float cj = cy[j];
      rk += (cj < my) || (cj == my && j < t);
    }
    perm[base + rk] = t & 255;
  }

  // gt matching
  {
    float area_b = (bx2 - bx1) * (by2 - by1);
    float best = -1.0f;
    int bidx = 0;
    const float* gt = gt_boxes + (size_t)n * G_GT * 4;
#pragma unroll 4
    for (int g = 0; g < G_GT; ++g) {
      float gx1 = gt[g * 4 + 0], gy1 = gt[g * 4 + 1];
      float gx2 = gt[g * 4 + 2], gy2 = gt[g * 4 + 3];
      float area_a = (gx2 - gx1) * (gy2 - gy1);
      float ix1 = fmaxf(gx1, bx1), iy1 = fmaxf(gy1, by1);
      float ix2 = fminf(gx2, bx2), iy2 = fminf(gy2, by2);
      float iw = fmaxf(ix2 - ix1, 0.0f), ih = fmaxf(iy2 - iy1, 0.0f);
      float inter = iw * ih;
      float iou = inter / fmaxf(area_a + area_b - inter, 1e-9f);
      if (iou > best) { best = iou; bidx = g; }
    }
    out_idx[t] = (float)bidx;
    out_lbl[t] = (best >= IOU_TH_F) ? 1.0f : 0.0f;
  }
}

// ---------------------------------------------------------------------------
// Kernel 2 (roi + partial heads): TWO blocks per proposal (channel halves),
// 1024 threads each; 8-way row split. Writes part[blk][h][85] (no bias).
// ---------------------------------------------------------------------------
__global__ __launch_bounds__(1024) void roihead_kernel(
    const float* __restrict__ features,   // (N, FH, FW, C)
    const float* __restrict__ proposals,  // (N, R, 4)
    const int* __restrict__ perm,         // (N*R) y-sorted order
    const float* __restrict__ W_cls,      // (C, 81)
    const float* __restrict__ W_box,      // (C, 4)
    float* __restrict__ part) {           // (N*R, 2, 85) partial logits
  const int b = blockIdx.x;             // 0..1023
  const int xcd = b & 7;
  const int slot = b >> 3;              // 0..127
  const int n = xcd >> 2;               // image
  const int band = xcd & 3;
  const int h = slot & 1;               // channel half
  const int blk = n * R_PROP + perm[n * R_PROP + band * 64 + (slot >> 1)];

  const float* feat = features + (size_t)n * (FH * FW * C_CH) + h * (C_CH / 2);
  const int t = threadIdx.x;
  const int c4 = t & 127;               // float4 slot within half (0..127)
  const int g = t >> 7;                 // 0..7 row group

  __shared__ float s_Wy[FH];
  __shared__ float s_Wx[FW];
  __shared__ int s_b[4];                // y_lo, y_hi, x_lo, x_hi
  __shared__ float4 s_red[7][128];
  __shared__ __align__(16) float sf[C_CH / 2];
  __shared__ float s_part[12][85];

  if (t < FH) s_Wy[t] = 0.0f;
  if (t >= 128 && t < 128 + FW) s_Wx[t - 128] = 0.0f;
  __syncthreads();

  if (t < 2 * P_POOL) {
    const float* pb = proposals + (size_t)blk * 4;
    bool isY = t < P_POOL;
    int i = isY ? t : t - P_POOL;
    float lo = isY ? pb[1] : pb[0];
    float hi = isY ? pb[3] : pb[2];
    float limit = isY ? (float)(FH - 1) : (float)(FW - 1);
    float b1 = lo * SCALE_F, b2 = hi * SCALE_F;
    float bs = (b2 - b1) * (1.0f / P_POOL);
    float gg = b1 + ((float)i + 0.5f) * bs - 0.5f;
    gg = fminf(fmaxf(gg, 0.0f), limit);
    float fl = floorf(gg);
    int i0 = (int)fl;
    int i1 = min(i0 + 1, (int)limit);
    float l = gg - fl;
    if (isY) {
      atomicAdd(&s_Wy[i0], 1.0f - l);
      atomicAdd(&s_Wy[i1], l);
      if (i == 0) s_b[0] = i0;
      if (i == P_POOL - 1) s_b[1] = i1;
    } else {
      atomicAdd(&s_Wx[i0], 1.0f - l);
      atomicAdd(&s_Wx[i1], l);
      if (i == 0) s_b[2] = i0;
      if (i == P_POOL - 1) s_b[3] = i1;
    }
  }
  __syncthreads();

  // ---- phase 1: ROI accumulate, 8-way row split over 512 channels ----
  {
    const int ylo = s_b[0], yhi = s_b[1], xlo = s_b[2], xhi = s_b[3];
    float4 acc = make_float4(0.f, 0.f, 0.f, 0.f);
    for (int y = ylo + g; y <= yhi; y += 8) {
      float wy = s_Wy[y];
      const float4* row = (const float4*)(feat + (size_t)y * (FW * C_CH)) + c4;
#pragma unroll 8
      for (int x = xlo; x <= xhi; ++x) {
        float w = wy * s_Wx[x];
        float4 f = row[x * (C_CH / 4)];
        acc.x += w * f.x;
        acc.y += w * f.y;
        acc.z += w * f.z;
        acc.w += w * f.w;
      }
    }
    if (g > 0) s_red[g - 1][c4] = acc;
    __syncthreads();
    if (g == 0) {
      const float inv = 1.0f / (float)(P_POOL * P_POOL);
#pragma unroll
      for (int p = 0; p < 7; ++p) {
        float4 a = s_red[p][c4];
        acc.x += a.x; acc.y += a.y; acc.z += a.z; acc.w += a.w;
      }
      ((float4*)sf)[c4] =
          make_float4(acc.x * inv, acc.y * inv, acc.z * inv, acc.w * inv);
    }
    __syncthreads();
  }

  // ---- phase 2: partial heads GEMV over this half's K=512, 12-way split ----
  const int kq = t / 85;        // 0..12 (t>=1020 -> 12, inactive)
  const int j = t - kq * 85;
  if (kq < 12) {
    float acc = 0.0f;
    const int kbase = h * (C_CH / 2);
    if (j < 81) {
      const float* __restrict__ w = W_cls + (size_t)kbase * 81 + j;
#pragma unroll 8
      for (int k = kq; k < C_CH / 2; k += 12) acc += sf[k] * w[k * 81];
    } else {
      const float* __restrict__ w = W_box + (size_t)kbase * 4 + (j - 81);
#pragma unroll 8
      for (int k = kq; k < C_CH / 2; k += 12) acc += sf[k] * w[k * 4];
    }
    s_part[kq][j] = acc;
  }
  __syncthreads();

  if (t < 85) {
    float acc = 0.0f;
#pragma unroll
    for (int p = 0; p < 12; ++p) acc += s_part[p][t];
    part[(size_t)blk * 170 + h * 85 + t] = acc;
  }
}

// ---------------------------------------------------------------------------
// Kernel 3 (finalize): one block per proposal, 128 threads. Assemble logits
// from the two halves + bias, shuffle-softmax, box decode. 512 blocks hide
// the part[] global reads at full occupancy (R6's proven heads epilogue).
// ---------------------------------------------------------------------------
__global__ __launch_bounds__(128) void finalize_kernel(
    const float* __restrict__ part,       // (N*R, 2, 85)
    const float* __restrict__ proposals,  // (N,R,4)
    const float* __restrict__ b_cls,      // (81)
    const float* __restrict__ b_box,      // (4)
    float* __restrict__ boxes_dec,        // (N*R, 4)
    float* __restrict__ scores) {         // (N*R)
  const int blk = blockIdx.x;   // 0..511
  const int t = threadIdx.x;
  __shared__ float sl[85];
  __shared__ float s_red[8];

  const float* pp = part + (size_t)blk * 170;
  if (t < 85) {
    float bias = (t < 81) ? b_cls[t] : b_box[t - 81];
    sl[t] = pp[t] + pp[85 + t] + bias;
  }
  __syncthreads();

  // parallel reductions over the 81 logits (2 waves cover 0..127)
  {
    float xm = (t < 81) ? sl[t] : -INFINITY;        // max over all 81
    float xf = (t < NCLS) ? sl[t] : -INFINITY;      // max over fg 80
#pragma unroll
    for (int off = 32; off; off >>= 1) {
      xm = fmaxf(xm, __shfl_down(xm, off, 64));
      xf = fmaxf(xf, __shfl_down(xf, off, 64));
    }
    if ((t & 63) == 0) { s_red[t >> 6] = xm; s_red[2 + (t >> 6)] = xf; }
  }
  __syncthreads();
  const float m = fmaxf(s_red[0], s_red[1]);
  {
    float xs = (t < 81) ? expf(sl[t] - m) : 0.0f;
#pragma unroll
    for (int off = 32; off; off >>= 1) xs += __shfl_down(xs, off, 64);
    if ((t & 63) == 0) s_red[4 + (t >> 6)] = xs;
  }
  __syncthreads();

  if (t == 0) {
    float sum = s_red[4] + s_red[5];
    float fgm = fmaxf(s_red[2], s_red[3]);
    scores[blk] = expf(fgm - m) / sum;

    const float* pb = proposals + (size_t)blk * 4;
    float w = pb[2] - pb[0], h = pb[3] - pb[1];
    float cx = pb[0] + 0.5f * w, cy = pb[1] + 0.5f * h;
    float dx = sl[81] * 0.1f;
    float dy = sl[82] * 0.1f;
    float dw = fminf(sl[83] * 0.2f, SCALE_CLAMP_F);
    float dh = fminf(sl[84] * 0.2f, SCALE_CLAMP_F);
    float pcx = dx * w + cx, pcy = dy * h + cy;
    float pw = expf(dw) * w, ph = expf(dh) * h;
    float ox1 = fminf(fmaxf(pcx - 0.5f * pw, 0.0f), IMG_W_F);
    float oy1 = fminf(fmaxf(pcy - 0.5f * ph, 0.0f), IMG_H_F);
    float ox2 = fminf(fmaxf(pcx + 0.5f * pw, 0.0f), IMG_W_F);
    float oy2 = fminf(fmaxf(pcy + 0.5f * ph, 0.0f), IMG_H_F);
    float* bd = boxes_dec + (size_t)blk * 4;
    bd[0] = ox1; bd[1] = oy1; bd[2] = ox2; bd[3] = oy2;
  }
}

// ---------------------------------------------------------------------------
// Kernel 4: greedy NMS + score filter + top-100 rank + det write (R7 version:
// LDS-only after the initial 256 box/score loads).
// ---------------------------------------------------------------------------
__global__ __launch_bounds__(1024) void nms_kernel(
    const float* __restrict__ boxes_dec,  // (N*R, 4)
    const float* __restrict__ scores,     // (N*R)
    float* __restrict__ det) {            // (N, R, 6)
  const int n = blockIdx.x;
  const int u = threadIdx.x;
  const int i = u & 255;
  const int q = u >> 8;           // 0..3
  const int j40 = q * 16;         // float4 index start for this quarter

  __shared__ __align__(16) float ss[R_PROP];     // scores, original order
  __shared__ float4 sbs[R_PROP];                 // sorted boxes
  __shared__ int s_part[4 * R_PROP];             // partial rank counts
  __shared__ int s_rank[R_PROP];
  __shared__ __align__(16) unsigned long long s_mask[R_PROP * 4];
  __shared__ unsigned long long s_keep[4];
  __shared__ __align__(16) float sm[R_PROP];     // masked scores, orig order

  float4 myb;
  float mys;
  if (q == 0) {
    myb = ((const float4*)boxes_dec)[n * R_PROP + i];
    mys = scores[n * R_PROP + i];
    ss[i] = mys;
  }
  __syncthreads();

  // stable descending rank (ties by original index): float4 loads, 16/thread
  {
    float s = ss[i];
    int cnt = 0;
#pragma unroll
    for (int j4 = j40; j4 < j40 + 16; ++j4) {
      float4 v = ((const float4*)ss)[j4];
      int jb = j4 * 4;
      cnt += (v.x > s) || (v.x == s && jb + 0 < i);
      cnt += (v.y > s) || (v.y == s && jb + 1 < i);
      cnt += (v.z > s) || (v.z == s && jb + 2 < i);
      cnt += (v.w > s) || (v.w == s && jb + 3 < i);
    }
    s_part[q * R_PROP + i] = cnt;
  }
  __syncthreads();
  if (q == 0) {
    int rk = s_part[i] + s_part[R_PROP + i] + s_part[2 * R_PROP + i] +
             s_part[3 * R_PROP + i];
    s_rank[i] = rk;
    sbs[rk] = myb;
  }
  __syncthreads();

  // phase 1: thread (i,q) computes mask word q of sorted box i vs sorted j
  {
    float4 bi = sbs[i];
    float area_i = (bi.z - bi.x) * (bi.w - bi.y);
    unsigned long long m = 0;
    const int j0 = q * 64;
#pragma unroll 8
    for (int jj = 0; jj < 64; ++jj) {
      float4 bj = sbs[j0 + jj];
      float area_j = (bj.z - bj.x) * (bj.w - bj.y);
      float ix1 = fmaxf(bi.x, bj.x), iy1 = fmaxf(bi.y, bj.y);
      float ix2 = fminf(bi.z, bj.z), iy2 = fminf(bi.w, bj.w);
      float iw = fmaxf(ix2 - ix1, 0.0f), ih = fmaxf(iy2 - iy1, 0.0f);
      float inter = iw * ih;
      float iou = inter / fmaxf(area_i + area_j - inter, 1e-9f);
      m |= (iou > NMS_TH_F) ? (1ull << jj) : 0ull;
    }
    s_mask[i * 4 + q] = m;
  }
  __syncthreads();

  // phase 2: branchless serial greedy pass over sorted order (thread 0).
  if (u == 0) {
    unsigned long long K0 = ~0ull, K1 = ~0ull, K2 = ~0ull, K3 = ~0ull;
#pragma unroll 16
    for (int b = 1; b < 64; ++b) {
      unsigned long long m0 = s_mask[(size_t)b * 4 + 0];
      unsigned long long sup = m0 & K0 & ((1ull << b) - 1ull);
      K0 = sup ? (K0 & ~(1ull << b)) : K0;
    }
#pragma unroll 16
    for (int b = 0; b < 64; ++b) {
      const unsigned long long* mi = &s_mask[(size_t)(64 + b) * 4];
      unsigned long long m0 = mi[0], m1 = mi[1];
      unsigned long long sup = (m0 & K0) | (m1 & K1 & ((1ull << b) - 1ull));
      K1 = sup ? (K1 & ~(1ull << b)) : K1;
    }
#pragma unroll 16
    for (int b = 0; b < 64; ++b) {
      const unsigned long long* mi = &s_mask[(size_t)(128 + b) * 4];
      unsigned long long m0 = mi[0], m1 = mi[1], m2 = mi[2];
      unsigned long long sup =
          (m0 & K0) | (m1 & K1) | (m2 & K2 & ((1ull << b) - 1ull));
      K2 = sup ? (K2 & ~(1ull << b)) : K2;
    }
#pragma unroll 16
    for (int b = 0; b < 64; ++b) {
      const unsigned long long* mi = &s_mask[(size_t)(192 + b) * 4];
      unsigned long long m0 = mi[0], m1 = mi[1], m2 = mi[2], m3 = mi[3];
      unsigned long long sup = (m0 & K0) | (m1 & K1) | (m2 & K2) |
                               (m3 & K3 & ((1ull << b) - 1ull));
      K3 = sup ? (K3 & ~(1ull << b)) : K3;
    }
    s_keep[0] = K0; s_keep[1] = K1; s_keep[2] = K2; s_keep[3] = K3;
  }
  __syncthreads();

  bool kept = false;
  if (q == 0) {
    int rk = s_rank[i];
    kept = ((s_keep[rk >> 6] >> (rk & 63)) & 1ull) && (mys > SCORE_TH_F);
    sm[i] = kept ? mys : -INFINITY;
  }
  __syncthreads();

  // top-100 rank over masked scores: float4 loads, 16/thread
  {
    float mym = sm[i];
    int cnt = 0;
#pragma unroll
    for (int j4 = j40; j4 < j40 + 16; ++j4) {
      float4 v = ((const float4*)sm)[j4];
      int jb = j4 * 4;
      cnt += (v.x > mym) || (v.x == mym && jb + 0 < i);
      cnt += (v.y > mym) || (v.y == mym && jb + 1 < i);
      cnt += (v.z > mym) || (v.z == mym && jb + 2 < i);
      cnt += (v.w > mym) || (v.w == mym && jb + 3 < i);
    }
    s_part[q * R_PROP + i] = cnt;
  }
  __syncthreads();

  if (q == 0) {
    int rk2 = s_part[i] + s_part[R_PROP + i] + s_part[2 * R_PROP + i] +
              s_part[3 * R_PROP + i];
    kept = kept && (rk2 < MAX_DET_I);
    float* dr = det + ((size_t)n * R_PROP + i) * 6;
    dr[0] = myb.x; dr[1] = myb.y; dr[2] = myb.z; dr[3] = myb.w;
    dr[4] = mys;
    dr[5] = kept ? 1.0f : 0.0f;
  }
}

// ---------------------------------------------------------------------------
extern "C" void kernel_launch(void* const* d_in, const int* in_sizes, int n_in,
                              void* d_out, int out_size, void* d_ws, size_t ws_size,
                              hipStream_t stream) {
  const float* features  = (const float*)d_in[0];  // (2,50,80,1024)
  const float* proposals = (const float*)d_in[1];  // (2,256,4)
  const float* gt_boxes  = (const float*)d_in[2];  // (2,64,4)
  // d_in[3] gt_classes: unused by reference outputs
  const float* W_cls = (const float*)d_in[4];      // (1024,81)
  const float* b_cls = (const float*)d_in[5];      // (81)
  const float* W_box = (const float*)d_in[6];      // (1024,4)
  const float* b_box = (const float*)d_in[7];      // (4)

  float* out = (float*)d_out;
  // out layout: det [0,3072) | matched_idxs [3072,3584) | match_labels [3584,4096)
  float* out_det = out;
  float* out_idx = out + N_IMG * R_PROP * 6;
  float* out_lbl = out_idx + N_IMG * R_PROP;

  // workspace layout
  float* part      = (float*)d_ws;                              // 512*170
  float* boxes_dec = part + (size_t)N_IMG * R_PROP * 170;       // 512*4
  float* scores    = boxes_dec + (size_t)N_IMG * R_PROP * 4;    // 512
  int*   perm      = (int*)(scores + N_IMG * R_PROP);           // 512

  prep_kernel<<<1, 512, 0, stream>>>(proposals, gt_boxes, perm, out_idx, out_lbl);
  roihead_kernel<<<2 * N_IMG * R_PROP, 1024, 0, stream>>>(
      features, proposals, perm, W_cls, W_box, part);
  finalize_kernel<<<N_IMG * R_PROP, 128, 0, stream>>>(
      part, proposals, b_cls, b_box, boxes_dec, scores);
  nms_kernel<<<N_IMG, 1024, 0, stream>>>(boxes_dec, scores, out_det);
}